// Round 9
// baseline (2725.743 us; speedup 1.0000x reference)
//
#include <hip/hip_runtime.h>

// Problem constants (fixed by the reference file)
#define NPTS 524288
#define NUMC 128
#define FD   8
#define NBLK 2048          // NPTS / 256
#define ITERS 5

// k_sums LDS ring: RING slots x 8 features x CSZ members
#define CSZ   512          // members per chunk per feature
#define FCOL  516          // column stride in floats: 2064B, 16B-aligned; 516%32=4 -> lanes 0..7 bank-disjoint
#define SLOTF (FD * FCOL)  // 4128 floats per slot
#define RING  3            // 49536 B LDS; 2-chunk DMA lead ~4000 cyc >> 900 cyc miss

static_assert(NPTS == NBLK * 256, "grid must tile N exactly");

#define WAITVM(N) asm volatile("s_waitcnt vmcnt(" #N ")" ::: "memory")

// hand-scheduled consume stanza: wait oldest of 16 in-flight ds_read_b128,
// 4 dependent adds (the bit-exact chain), re-issue the read, advance addr.
#define ST(A,B,C,D) \
  "s_waitcnt lgkmcnt(15)\n\t" \
  "v_add_f32 %[acc], %[acc], v" #A "\n\t" \
  "v_add_f32 %[acc], %[acc], v" #B "\n\t" \
  "v_add_f32 %[acc], %[acc], v" #C "\n\t" \
  "v_add_f32 %[acc], %[acc], v" #D "\n\t" \
  "ds_read_b128 v[" #A ":" #D "], v66\n\t" \
  "v_add_u32 v66, 16, v66\n\t"

#define DR(N,A,B,C,D) \
  "s_waitcnt lgkmcnt(" #N ")\n\t" \
  "v_add_f32 %[acc], %[acc], v" #A "\n\t" \
  "v_add_f32 %[acc], %[acc], v" #B "\n\t" \
  "v_add_f32 %[acc], %[acc], v" #C "\n\t" \
  "v_add_f32 %[acc], %[acc], v" #D "\n\t"

__global__ void k_init(const float* __restrict__ cin, float* __restrict__ cen, int* __restrict__ flag) {
    int t = blockIdx.x * 256 + threadIdx.x;
    if (t < NUMC * FD) cen[t] = cin[t];
    if (t == 0) *flag = 0;
}

__global__ void k_zero(int* __restrict__ cnt_inr) {
    int t = threadIdx.x;
    if (t < NUMC) cnt_inr[t] = 0;
}

// Pass A: per-center count of points with sqrt(dx^2+dy^2) <= 0.32
__global__ void k_count(const float* __restrict__ data, const float* __restrict__ cen,
                        int* __restrict__ cnt_inr, const int* __restrict__ flag) {
    if (*flag) return;
    __shared__ float cx[NUMC], cy[NUMC];
    __shared__ int hist[NUMC];
    int tid = threadIdx.x;
    if (tid < NUMC) { cx[tid] = cen[tid * FD]; cy[tid] = cen[tid * FD + 1]; hist[tid] = 0; }
    __syncthreads();
    size_t j = (size_t)blockIdx.x * 256 + tid;
    float2 p = *(const float2*)(data + j * FD);
    int lane = tid & 63;
    for (int i = 0; i < NUMC; i++) {
        float dx = __fsub_rn(p.x, cx[i]);
        float dy = __fsub_rn(p.y, cy[i]);
        float s  = __fadd_rn(__fmul_rn(dx, dx), __fmul_rn(dy, dy));
        bool in  = (__fsqrt_rn(s) <= 0.32f);
        unsigned long long m = __ballot(in);
        if (lane == 0 && m) atomicAdd(&hist[i], __popcll(m));
    }
    __syncthreads();
    if (tid < NUMC && hist[tid]) atomicAdd(&cnt_inr[tid], hist[tid]);
}

// Pass B: sequential-per-center assignment chain with the freeze quirk.
__global__ void k_assign(const float* __restrict__ data, const float* __restrict__ cen,
                         const int* __restrict__ cnt_inr, int* __restrict__ labels,
                         int* __restrict__ blockhist, const int* __restrict__ flag) {
    if (*flag) return;
    __shared__ float C[NUMC * FD];
    __shared__ int enough[NUMC];
    __shared__ int hist[NUMC];
    int tid = threadIdx.x;
    for (int e = tid; e < NUMC * FD; e += 256) C[e] = cen[e];
    if (tid < NUMC) { enough[tid] = (cnt_inr[tid] > 1); hist[tid] = 0; }
    __syncthreads();
    size_t j = (size_t)blockIdx.x * 256 + tid;
    float4 a = *(const float4*)(data + j * FD);
    float4 b = *(const float4*)(data + j * FD + 4);
    float x[8] = {a.x, a.y, a.z, a.w, b.x, b.y, b.z, b.w};
    int lab = -1;
    float dval = 1000.0f;
    for (int i = 0; i < NUMC; i++) {
        const float* c = &C[i * FD];
        float dx = __fsub_rn(x[0], c[0]);
        float dy = __fsub_rn(x[1], c[1]);
        float s  = __fadd_rn(__fmul_rn(dx, dx), __fmul_rn(dy, dy));
        float sp = __fsqrt_rn(s);
        if (sp <= 0.32f && enough[i]) {
            float t0 = __fadd_rn(__fsub_rn(x[0], c[0]), 1e-6f);
            float ss = __fmul_rn(t0, t0);
            #pragma unroll
            for (int f = 1; f < 8; f++) {
                float tf = __fadd_rn(__fsub_rn(x[f], c[f]), 1e-6f);
                ss = __fadd_rn(ss, __fmul_rn(tf, tf));
            }
            float D = __fsqrt_rn(ss);
            if (D < dval) { dval = D; lab = i; }
            else break;   // reference sets dval=0 -> frozen forever
        }
    }
    labels[j] = lab;
    if (lab >= 0) atomicAdd(&hist[lab], 1);
    __syncthreads();
    if (tid < NUMC) blockhist[tid * NBLK + blockIdx.x] = hist[tid];
}

// Per-cluster exclusive scan over the 2048 block counts
__global__ void k_scan(int* __restrict__ blockhist, int* __restrict__ ctot, const int* __restrict__ flag) {
    if (*flag) return;
    int c = blockIdx.x, tid = threadIdx.x;
    __shared__ int ts[256];
    int base = c * NBLK + tid * 8;
    int v[8], s = 0;
    #pragma unroll
    for (int u = 0; u < 8; u++) { v[u] = blockhist[base + u]; s += v[u]; }
    ts[tid] = s;
    __syncthreads();
    for (int off = 1; off < 256; off <<= 1) {
        int t = (tid >= off) ? ts[tid - off] : 0;
        __syncthreads();
        ts[tid] += t;
        __syncthreads();
    }
    int run = (tid == 0) ? 0 : ts[tid - 1];
    #pragma unroll
    for (int u = 0; u < 8; u++) { int t = v[u]; blockhist[base + u] = run; run += t; }
    if (tid == 255) ctot[c] = run;
}

__global__ void k_base(const int* __restrict__ ctot, int* __restrict__ cbase, const int* __restrict__ flag) {
    if (*flag) return;
    if (threadIdx.x == 0) {
        int r = 0;
        for (int c = 0; c < NUMC; c++) { cbase[c] = r; r += ctot[c]; }
        cbase[NUMC] = r;   // total assigned points
    }
}

// Stable scatter: member indices per cluster, ascending global point index
__global__ void k_scatter(const int* __restrict__ labels, const int* __restrict__ blockhist,
                          const int* __restrict__ cbase, int* __restrict__ idxlist,
                          const int* __restrict__ flag) {
    if (*flag) return;
    __shared__ int sl[256];
    int tid = threadIdx.x;
    int j = blockIdx.x * 256 + tid;
    sl[tid] = labels[j];
    __syncthreads();
    int c = sl[tid];
    if (c >= 0) {
        int rank = 0;
        for (int t = 0; t < tid; t++) rank += (sl[t] == c);
        idxlist[cbase[c] + blockhist[c * NBLK + blockIdx.x] + rank] = j;
    }
}

// Materialize member-ordered data feature-major: sorted[f][pos] = data[idxlist[pos]][f].
__global__ void k_reorder(const float* __restrict__ data, const int* __restrict__ idxlist,
                          const int* __restrict__ cbase, float* __restrict__ sorted,
                          const int* __restrict__ flag) {
    if (*flag) return;
    int pos = blockIdx.x * 256 + threadIdx.x;
    if (pos >= cbase[NUMC]) return;
    int rid = idxlist[pos];
    float4 a = *(const float4*)(data + (size_t)rid * FD);
    float4 b = *(const float4*)(data + (size_t)rid * FD + 4);
    sorted[(size_t)0 * NPTS + pos] = a.x;
    sorted[(size_t)1 * NPTS + pos] = a.y;
    sorted[(size_t)2 * NPTS + pos] = a.z;
    sorted[(size_t)3 * NPTS + pos] = a.w;
    sorted[(size_t)4 * NPTS + pos] = b.x;
    sorted[(size_t)5 * NPTS + pos] = b.y;
    sorted[(size_t)6 * NPTS + pos] = b.z;
    sorted[(size_t)7 * NPTS + pos] = b.w;
}

// Stage one 512-member chunk (all 8 features) into an LDS ring slot via async
// DMA: 16 x global_load_lds(16B/lane), no VGPR cost.
__device__ __forceinline__ void stage_chunk(const float* __restrict__ srt, int baseA,
                                            int t, int slot, float* sbuf, int lane) {
    const float* g0 = srt + (size_t)baseA + (size_t)t * CSZ + lane * 4;
    float* l0 = sbuf + slot * SLOTF;
    #pragma unroll
    for (int f = 0; f < FD; f++) {
        __builtin_amdgcn_global_load_lds(
            (const __attribute__((address_space(1))) void*)(g0 + (size_t)f * NPTS),
            (__attribute__((address_space(3))) void*)(l0 + f * FCOL),
            16, 0, 0);
        __builtin_amdgcn_global_load_lds(
            (const __attribute__((address_space(1))) void*)(g0 + (size_t)f * NPTS + 256),
            (__attribute__((address_space(3))) void*)(l0 + f * FCOL + 256),
            16, 0, 0);
    }
}

#define ADD4(v) { acc = __fadd_rn(acc, (v).x); acc = __fadd_rn(acc, (v).y); \
                  acc = __fadd_rn(acc, (v).z); acc = __fadd_rn(acc, (v).w); }

// Exact sequential fp32 segment sums: one wave per cluster. 2-chunk async DMA
// lead hides global latency; chain lanes 0..7 consume each 512-member chunk
// via a HAND-SCHEDULED asm pipeline: 16 ds_read_b128 in flight (v0..v63),
// stanza = waitcnt lgkmcnt(15) -> 4 dependent v_add_f32 -> reissue read.
// In-order DS return makes lgkmcnt(15) exactly "oldest landed". Add order
// identical to the reference scatter-add -> bit-exact.
__global__ void __launch_bounds__(64) k_sums(const float* __restrict__ sorted,
                       const int* __restrict__ cbase, const int* __restrict__ ctot,
                       float* __restrict__ sums, const int* __restrict__ flag) {
    if (*flag) return;
    __shared__ float sbuf[RING * SLOTF];
    int c = blockIdx.x;
    int lane = threadIdx.x;
    int m = ctot[c], base = cbase[c];
    float acc = 0.0f;
    const float* col = sorted + (size_t)lane * NPTS + base;   // lane<8 chain column

    int A = (4 - (base & 3)) & 3;          // scalar prologue to 16B alignment
    if (A > m) A = m;
    if (lane < FD)
        for (int k = 0; k < A; k++) acc = __fadd_rn(acc, col[k]);

    int baseA = base + A;
    int nch = (m - A) / CSZ;               // full 512-member chunks

    int pre = nch < RING ? nch : RING;
    for (int t = 0; t < pre; t++) stage_chunk(sorted, baseA, t, t, sbuf, lane);

    int slot = 0;
    for (int t = 0; t < nch; t++) {
        if (t >= 1 && t + 2 < nch)
            stage_chunk(sorted, baseA, t + 2, slot == 0 ? 2 : slot - 1, sbuf, lane);
        int K = nch - 1 - t; if (K > 2) K = 2;   // chunks staged beyond t
        switch (K) {
            case 0: WAITVM(0);  break;
            case 1: WAITVM(16); break;
            default: WAITVM(32); break;
        }
        if (lane < FD) {
            const float* lcol = sbuf + slot * SLOTF + lane * FCOL;
            unsigned a32 = (unsigned)(uintptr_t)
                (__attribute__((address_space(3))) const float*)lcol;
            asm volatile(
                "s_waitcnt lgkmcnt(0)\n\t"
                "v_mov_b32 v66, %[a]\n\t"
                "ds_read_b128 v[0:3], v66\n\t"
                "ds_read_b128 v[4:7], v66 offset:16\n\t"
                "ds_read_b128 v[8:11], v66 offset:32\n\t"
                "ds_read_b128 v[12:15], v66 offset:48\n\t"
                "ds_read_b128 v[16:19], v66 offset:64\n\t"
                "ds_read_b128 v[20:23], v66 offset:80\n\t"
                "ds_read_b128 v[24:27], v66 offset:96\n\t"
                "ds_read_b128 v[28:31], v66 offset:112\n\t"
                "ds_read_b128 v[32:35], v66 offset:128\n\t"
                "ds_read_b128 v[36:39], v66 offset:144\n\t"
                "ds_read_b128 v[40:43], v66 offset:160\n\t"
                "ds_read_b128 v[44:47], v66 offset:176\n\t"
                "ds_read_b128 v[48:51], v66 offset:192\n\t"
                "ds_read_b128 v[52:55], v66 offset:208\n\t"
                "ds_read_b128 v[56:59], v66 offset:224\n\t"
                "ds_read_b128 v[60:63], v66 offset:240\n\t"
                "v_add_u32 v66, 0x100, v66\n\t"
                "s_mov_b32 s20, 7\n\t"
                "L_%=:\n\t"
                ST(0,1,2,3)     ST(4,5,6,7)     ST(8,9,10,11)   ST(12,13,14,15)
                ST(16,17,18,19) ST(20,21,22,23) ST(24,25,26,27) ST(28,29,30,31)
                ST(32,33,34,35) ST(36,37,38,39) ST(40,41,42,43) ST(44,45,46,47)
                ST(48,49,50,51) ST(52,53,54,55) ST(56,57,58,59) ST(60,61,62,63)
                "s_sub_u32 s20, s20, 1\n\t"
                "s_cmp_lg_u32 s20, 0\n\t"
                "s_cbranch_scc1 L_%=\n\t"
                DR(15,0,1,2,3)     DR(14,4,5,6,7)     DR(13,8,9,10,11)   DR(12,12,13,14,15)
                DR(11,16,17,18,19) DR(10,20,21,22,23) DR(9,24,25,26,27)  DR(8,28,29,30,31)
                DR(7,32,33,34,35)  DR(6,36,37,38,39)  DR(5,40,41,42,43)  DR(4,44,45,46,47)
                DR(3,48,49,50,51)  DR(2,52,53,54,55)  DR(1,56,57,58,59)  DR(0,60,61,62,63)
                : [acc] "+v"(acc)
                : [a] "v"(a32)
                : "v0","v1","v2","v3","v4","v5","v6","v7",
                  "v8","v9","v10","v11","v12","v13","v14","v15",
                  "v16","v17","v18","v19","v20","v21","v22","v23",
                  "v24","v25","v26","v27","v28","v29","v30","v31",
                  "v32","v33","v34","v35","v36","v37","v38","v39",
                  "v40","v41","v42","v43","v44","v45","v46","v47",
                  "v48","v49","v50","v51","v52","v53","v54","v55",
                  "v56","v57","v58","v59","v60","v61","v62","v63",
                  "v66","s20","scc","memory");
        }
        slot = (slot == RING - 1) ? 0 : slot + 1;
    }

    // tail: members [A + nch*CSZ, m) from global, float4 depth-16 pipe (aligned)
    if (lane < FD) {
        int start = A + nch * CSZ;
        int rem = m - start;
        const float* tcol = col + start;
        int tv = rem >> 2;
        const float4* tvp = (const float4*)tcol;
        float4 tb[16];
        #pragma unroll
        for (int d = 0; d < 16; d++) if (d < tv) tb[d] = tvp[d];
        int u = 0;
        for (; u + 32 <= tv; u += 16) {
            #pragma unroll
            for (int d = 0; d < 16; d++) {
                float4 v = tb[d];
                ADD4(v);
                tb[d] = tvp[u + 16 + d];
            }
        }
        #pragma unroll
        for (int d = 0; d < 16; d++) {
            if (u + d < tv) {
                float4 v = tb[d];
                ADD4(v);
                if (u + 16 + d < tv) tb[d] = tvp[u + 16 + d];
            }
        }
        u += 16;
        #pragma unroll
        for (int d = 0; d < 16; d++) {
            if (u + d < tv) { float4 v = tb[d]; ADD4(v); }
        }
        for (int k = tv << 2; k < rem; k++) acc = __fadd_rn(acc, tcol[k]);
        sums[c * FD + lane] = acc;
    }
}

// Center update + convergence flag (1 block)
__global__ void k_update(float* __restrict__ cen, const float* __restrict__ sums,
                         const int* __restrict__ ctot, int* __restrict__ flag) {
    if (*flag) return;
    __shared__ float red[256];
    int tid = threadIdx.x;
    float sq = 0.0f;
    float newv[4];
    int   eidx[4];
    int ne = 0;
    for (int e = tid; e < NUMC * FD; e += 256) {
        int c = e >> 3;
        float oldv = cen[e];
        float cntf = (float)ctot[c];
        float mean = __fdiv_rn(sums[e], fmaxf(cntf, 1.0f));
        float nc = (cntf > 0.0f) ? mean : oldv;
        float d = __fsub_rn(nc, oldv);
        sq = __fadd_rn(sq, __fmul_rn(d, d));
        newv[ne] = nc; eidx[ne] = e; ne++;
    }
    red[tid] = sq;
    __syncthreads();
    for (int off = 128; off > 0; off >>= 1) {
        if (tid < off) red[tid] += red[tid + off];
        __syncthreads();
    }
    for (int u = 0; u < ne; u++) cen[eidx[u]] = newv[u];
    if (tid == 0) {
        float diff = __fsqrt_rn(red[0]);
        if (diff < 1e-4f) *flag = 1;
    }
}

// Finalize: labels staged as int32 in d_out[0..N); convert to float, append centers.
__global__ void k_finish(float* __restrict__ out, const float* __restrict__ cen) {
    size_t i = (size_t)blockIdx.x * 256 + threadIdx.x;
    if (i < NPTS) {
        int v = ((const int*)out)[i];
        out[i] = (float)v;
    } else if (i < NPTS + NUMC * FD) {
        out[i] = cen[i - NPTS];
    }
}

extern "C" void kernel_launch(void* const* d_in, const int* in_sizes, int n_in,
                              void* d_out, int out_size, void* d_ws, size_t ws_size,
                              hipStream_t stream) {
    const float* data = (const float*)d_in[0];
    const float* cen0 = (const float*)d_in[1];
    float* out = (float*)d_out;
    char* ws = (char*)d_ws;

    float* wcen   = (float*)(ws + 0);
    int*   flag   = (int*)(ws + 4096);
    int*   cntinr = (int*)(ws + 8192);
    int*   ctot   = (int*)(ws + 8704);
    int*   cbase  = (int*)(ws + 9216);    // 129 ints
    float* sums   = (float*)(ws + 10240);
    int*   bh     = (int*)(ws + 16384);
    int*   idxl   = (int*)(ws + 16384 + (size_t)NUMC * NBLK * 4);
    float* sorted = (float*)(ws + 16384 + (size_t)NUMC * NBLK * 4 + (size_t)NPTS * 4);
    int*   labels = (int*)d_out;   // staged as int32, converted by k_finish

    k_init<<<4, 256, 0, stream>>>(cen0, wcen, flag);
    for (int it = 0; it < ITERS; ++it) {
        k_zero   <<<1, 256, 0, stream>>>(cntinr);
        k_count  <<<NBLK, 256, 0, stream>>>(data, wcen, cntinr, flag);
        k_assign <<<NBLK, 256, 0, stream>>>(data, wcen, cntinr, labels, bh, flag);
        k_scan   <<<NUMC, 256, 0, stream>>>(bh, ctot, flag);
        k_base   <<<1, 64, 0, stream>>>(ctot, cbase, flag);
        k_scatter<<<NBLK, 256, 0, stream>>>(labels, bh, cbase, idxl, flag);
        k_reorder<<<NBLK, 256, 0, stream>>>(data, idxl, cbase, sorted, flag);
        k_sums   <<<NUMC, 64, 0, stream>>>(sorted, cbase, ctot, sums, flag);
        k_update <<<1, 256, 0, stream>>>(wcen, sums, ctot, flag);
    }
    k_finish<<<(NPTS + NUMC * FD + 255) / 256, 256, 0, stream>>>(out, wcen);
}

// Round 10
// 2274.983 us; speedup vs baseline: 1.1981x; 1.1981x over previous
//
#include <hip/hip_runtime.h>

// Problem constants (fixed by the reference file)
#define NPTS 524288
#define NUMC 128
#define FD   8
#define NBLK 2048          // NPTS / 256
#define ITERS 5

// k_sums LDS ring: RING slots x 8 features x CSZ members
#define CSZ   512          // members per chunk per feature
#define FCOL  516          // column stride in floats: 2064B, 16B-aligned; 516%32=4 -> lanes 0..7 bank-disjoint
#define SLOTF (FD * FCOL)  // 4128 floats per slot
#define RING  3            // 49536 B LDS; 2-chunk DMA lead ~4000 cyc >> 900 cyc miss

static_assert(NPTS == NBLK * 256, "grid must tile N exactly");

#define WAITVM(N) asm volatile("s_waitcnt vmcnt(" #N ")" ::: "memory")

__global__ void k_init(const float* __restrict__ cin, float* __restrict__ cen,
                       int* __restrict__ flag, int* __restrict__ cnt_inr) {
    int t = blockIdx.x * 256 + threadIdx.x;
    if (t < NUMC * FD) cen[t] = cin[t];
    if (t < NUMC) cnt_inr[t] = 0;
    if (t == 0) *flag = 0;
}

// Pass A: per-center count of points with sqrt(dx^2+dy^2) <= 0.32
__global__ void k_count(const float* __restrict__ data, const float* __restrict__ cen,
                        int* __restrict__ cnt_inr, const int* __restrict__ flag) {
    if (*flag) return;
    __shared__ float cx[NUMC], cy[NUMC];
    __shared__ int hist[NUMC];
    int tid = threadIdx.x;
    if (tid < NUMC) { cx[tid] = cen[tid * FD]; cy[tid] = cen[tid * FD + 1]; hist[tid] = 0; }
    __syncthreads();
    size_t j = (size_t)blockIdx.x * 256 + tid;
    float2 p = *(const float2*)(data + j * FD);
    int lane = tid & 63;
    for (int i = 0; i < NUMC; i++) {
        float dx = __fsub_rn(p.x, cx[i]);
        float dy = __fsub_rn(p.y, cy[i]);
        float s  = __fadd_rn(__fmul_rn(dx, dx), __fmul_rn(dy, dy));
        bool in  = (__fsqrt_rn(s) <= 0.32f);
        unsigned long long m = __ballot(in);
        if (lane == 0 && m) atomicAdd(&hist[i], __popcll(m));
    }
    __syncthreads();
    if (tid < NUMC && hist[tid]) atomicAdd(&cnt_inr[tid], hist[tid]);
}

// Pass B: sequential-per-center assignment chain with the freeze quirk.
__global__ void k_assign(const float* __restrict__ data, const float* __restrict__ cen,
                         const int* __restrict__ cnt_inr, int* __restrict__ labels,
                         int* __restrict__ blockhist, const int* __restrict__ flag) {
    if (*flag) return;
    __shared__ float C[NUMC * FD];
    __shared__ int enough[NUMC];
    __shared__ int hist[NUMC];
    int tid = threadIdx.x;
    for (int e = tid; e < NUMC * FD; e += 256) C[e] = cen[e];
    if (tid < NUMC) { enough[tid] = (cnt_inr[tid] > 1); hist[tid] = 0; }
    __syncthreads();
    size_t j = (size_t)blockIdx.x * 256 + tid;
    float4 a = *(const float4*)(data + j * FD);
    float4 b = *(const float4*)(data + j * FD + 4);
    float x[8] = {a.x, a.y, a.z, a.w, b.x, b.y, b.z, b.w};
    int lab = -1;
    float dval = 1000.0f;
    for (int i = 0; i < NUMC; i++) {
        const float* c = &C[i * FD];
        float dx = __fsub_rn(x[0], c[0]);
        float dy = __fsub_rn(x[1], c[1]);
        float s  = __fadd_rn(__fmul_rn(dx, dx), __fmul_rn(dy, dy));
        float sp = __fsqrt_rn(s);
        if (sp <= 0.32f && enough[i]) {
            float t0 = __fadd_rn(__fsub_rn(x[0], c[0]), 1e-6f);
            float ss = __fmul_rn(t0, t0);
            #pragma unroll
            for (int f = 1; f < 8; f++) {
                float tf = __fadd_rn(__fsub_rn(x[f], c[f]), 1e-6f);
                ss = __fadd_rn(ss, __fmul_rn(tf, tf));
            }
            float D = __fsqrt_rn(ss);
            if (D < dval) { dval = D; lab = i; }
            else break;   // reference sets dval=0 -> frozen forever
        }
    }
    labels[j] = lab;
    if (lab >= 0) atomicAdd(&hist[lab], 1);
    __syncthreads();
    if (tid < NUMC) blockhist[tid * NBLK + blockIdx.x] = hist[tid];
}

// Per-cluster exclusive scan over the 2048 block counts
__global__ void k_scan(int* __restrict__ blockhist, int* __restrict__ ctot, const int* __restrict__ flag) {
    if (*flag) return;
    int c = blockIdx.x, tid = threadIdx.x;
    __shared__ int ts[256];
    int base = c * NBLK + tid * 8;
    int v[8], s = 0;
    #pragma unroll
    for (int u = 0; u < 8; u++) { v[u] = blockhist[base + u]; s += v[u]; }
    ts[tid] = s;
    __syncthreads();
    for (int off = 1; off < 256; off <<= 1) {
        int t = (tid >= off) ? ts[tid - off] : 0;
        __syncthreads();
        ts[tid] += t;
        __syncthreads();
    }
    int run = (tid == 0) ? 0 : ts[tid - 1];
    #pragma unroll
    for (int u = 0; u < 8; u++) { int t = v[u]; blockhist[base + u] = run; run += t; }
    if (tid == 255) ctot[c] = run;
}

__global__ void k_base(const int* __restrict__ ctot, int* __restrict__ cbase, const int* __restrict__ flag) {
    if (*flag) return;
    if (threadIdx.x == 0) {
        int r = 0;
        for (int c = 0; c < NUMC; c++) { cbase[c] = r; r += ctot[c]; }
        cbase[NUMC] = r;   // total assigned points
    }
}

// Fused stable scatter + feature-major materialization: thread j computes its
// stable position and writes its 8 features directly into the sorted columns.
__global__ void k_scatter(const float* __restrict__ data, const int* __restrict__ labels,
                          const int* __restrict__ blockhist, const int* __restrict__ cbase,
                          float* __restrict__ sorted, const int* __restrict__ flag) {
    if (*flag) return;
    __shared__ int sl[256];
    int tid = threadIdx.x;
    int j = blockIdx.x * 256 + tid;
    sl[tid] = labels[j];
    __syncthreads();
    int c = sl[tid];
    if (c >= 0) {
        int rank = 0;
        for (int t = 0; t < tid; t++) rank += (sl[t] == c);
        int pos = cbase[c] + blockhist[c * NBLK + blockIdx.x] + rank;
        float4 a = *(const float4*)(data + (size_t)j * FD);
        float4 b = *(const float4*)(data + (size_t)j * FD + 4);
        sorted[(size_t)0 * NPTS + pos] = a.x;
        sorted[(size_t)1 * NPTS + pos] = a.y;
        sorted[(size_t)2 * NPTS + pos] = a.z;
        sorted[(size_t)3 * NPTS + pos] = a.w;
        sorted[(size_t)4 * NPTS + pos] = b.x;
        sorted[(size_t)5 * NPTS + pos] = b.y;
        sorted[(size_t)6 * NPTS + pos] = b.z;
        sorted[(size_t)7 * NPTS + pos] = b.w;
    }
}

// Stage one 512-member chunk (all 8 features) into an LDS ring slot via async
// DMA: 16 x global_load_lds(16B/lane), no VGPR cost.
__device__ __forceinline__ void stage_chunk(const float* __restrict__ srt, int baseA,
                                            int t, int slot, float* sbuf, int lane) {
    const float* g0 = srt + (size_t)baseA + (size_t)t * CSZ + lane * 4;
    float* l0 = sbuf + slot * SLOTF;
    #pragma unroll
    for (int f = 0; f < FD; f++) {
        __builtin_amdgcn_global_load_lds(
            (const __attribute__((address_space(1))) void*)(g0 + (size_t)f * NPTS),
            (__attribute__((address_space(3))) void*)(l0 + f * FCOL),
            16, 0, 0);
        __builtin_amdgcn_global_load_lds(
            (const __attribute__((address_space(1))) void*)(g0 + (size_t)f * NPTS + 256),
            (__attribute__((address_space(3))) void*)(l0 + f * FCOL + 256),
            16, 0, 0);
    }
}

#define ADD4(v) { acc = __fadd_rn(acc, (v).x); acc = __fadd_rn(acc, (v).y); \
                  acc = __fadd_rn(acc, (v).z); acc = __fadd_rn(acc, (v).w); }

// Exact sequential fp32 segment sums: one wave per cluster. 2-chunk async DMA
// lead hides global latency; chain lanes 0..7 consume via the compiler-
// scheduled 32-deep ds_read_b128 pipe (R8's proven-best schedule: ~6 cyc per
// member = single-wave dependent v_add_f32 latency floor). Add order identical
// to the reference scatter-add -> bit-exact.
__global__ void __launch_bounds__(64) k_sums(const float* __restrict__ sorted,
                       const int* __restrict__ cbase, const int* __restrict__ ctot,
                       float* __restrict__ sums, const int* __restrict__ flag) {
    if (*flag) return;
    __shared__ float sbuf[RING * SLOTF];
    int c = blockIdx.x;
    int lane = threadIdx.x;
    int m = ctot[c], base = cbase[c];
    float acc = 0.0f;
    const float* col = sorted + (size_t)lane * NPTS + base;   // lane<8 chain column

    int A = (4 - (base & 3)) & 3;          // scalar prologue to 16B alignment
    if (A > m) A = m;
    if (lane < FD)
        for (int k = 0; k < A; k++) acc = __fadd_rn(acc, col[k]);

    int baseA = base + A;
    int nch = (m - A) / CSZ;               // full 512-member chunks

    int pre = nch < RING ? nch : RING;
    for (int t = 0; t < pre; t++) stage_chunk(sorted, baseA, t, t, sbuf, lane);

    int slot = 0;
    for (int t = 0; t < nch; t++) {
        if (t >= 1 && t + 2 < nch)
            stage_chunk(sorted, baseA, t + 2, slot == 0 ? 2 : slot - 1, sbuf, lane);
        int K = nch - 1 - t; if (K > 2) K = 2;   // chunks staged beyond t
        switch (K) {
            case 0: WAITVM(0);  break;
            case 1: WAITVM(16); break;
            default: WAITVM(32); break;
        }
        if (lane < FD) {
            const float* lcol = sbuf + slot * SLOTF + lane * FCOL;
            const float4* lv = (const float4*)lcol;
            float4 q[32];
            #pragma unroll
            for (int d = 0; d < 32; d++) q[d] = lv[d];
            #pragma unroll 32
            for (int b = 0; b < 96; b++) {
                float4 v = q[b & 31];
                ADD4(v);
                q[b & 31] = lv[b + 32];
            }
            #pragma unroll
            for (int b = 96; b < 128; b++) { float4 v = q[b & 31]; ADD4(v); }
        }
        slot = (slot == RING - 1) ? 0 : slot + 1;
    }

    // tail: members [A + nch*CSZ, m) from global, float4 depth-16 pipe (aligned)
    if (lane < FD) {
        int start = A + nch * CSZ;
        int rem = m - start;
        const float* tcol = col + start;
        int tv = rem >> 2;
        const float4* tvp = (const float4*)tcol;
        float4 tb[16];
        #pragma unroll
        for (int d = 0; d < 16; d++) if (d < tv) tb[d] = tvp[d];
        int u = 0;
        for (; u + 32 <= tv; u += 16) {
            #pragma unroll
            for (int d = 0; d < 16; d++) {
                float4 v = tb[d];
                ADD4(v);
                tb[d] = tvp[u + 16 + d];
            }
        }
        #pragma unroll
        for (int d = 0; d < 16; d++) {
            if (u + d < tv) {
                float4 v = tb[d];
                ADD4(v);
                if (u + 16 + d < tv) tb[d] = tvp[u + 16 + d];
            }
        }
        u += 16;
        #pragma unroll
        for (int d = 0; d < 16; d++) {
            if (u + d < tv) { float4 v = tb[d]; ADD4(v); }
        }
        for (int k = tv << 2; k < rem; k++) acc = __fadd_rn(acc, tcol[k]);
        sums[c * FD + lane] = acc;
    }
}

// Center update + convergence flag (1 block); also zeroes cnt_inr for the
// next iteration (replaces the separate k_zero launch).
__global__ void k_update(float* __restrict__ cen, const float* __restrict__ sums,
                         const int* __restrict__ ctot, int* __restrict__ flag,
                         int* __restrict__ cnt_inr) {
    if (*flag) return;
    __shared__ float red[256];
    int tid = threadIdx.x;
    if (tid < NUMC) cnt_inr[tid] = 0;
    float sq = 0.0f;
    float newv[4];
    int   eidx[4];
    int ne = 0;
    for (int e = tid; e < NUMC * FD; e += 256) {
        int c = e >> 3;
        float oldv = cen[e];
        float cntf = (float)ctot[c];
        float mean = __fdiv_rn(sums[e], fmaxf(cntf, 1.0f));
        float nc = (cntf > 0.0f) ? mean : oldv;
        float d = __fsub_rn(nc, oldv);
        sq = __fadd_rn(sq, __fmul_rn(d, d));
        newv[ne] = nc; eidx[ne] = e; ne++;
    }
    red[tid] = sq;
    __syncthreads();
    for (int off = 128; off > 0; off >>= 1) {
        if (tid < off) red[tid] += red[tid + off];
        __syncthreads();
    }
    for (int u = 0; u < ne; u++) cen[eidx[u]] = newv[u];
    if (tid == 0) {
        float diff = __fsqrt_rn(red[0]);
        if (diff < 1e-4f) *flag = 1;
    }
}

// Finalize: labels staged as int32 in d_out[0..N); convert to float, append centers.
__global__ void k_finish(float* __restrict__ out, const float* __restrict__ cen) {
    size_t i = (size_t)blockIdx.x * 256 + threadIdx.x;
    if (i < NPTS) {
        int v = ((const int*)out)[i];
        out[i] = (float)v;
    } else if (i < NPTS + NUMC * FD) {
        out[i] = cen[i - NPTS];
    }
}

extern "C" void kernel_launch(void* const* d_in, const int* in_sizes, int n_in,
                              void* d_out, int out_size, void* d_ws, size_t ws_size,
                              hipStream_t stream) {
    const float* data = (const float*)d_in[0];
    const float* cen0 = (const float*)d_in[1];
    float* out = (float*)d_out;
    char* ws = (char*)d_ws;

    float* wcen   = (float*)(ws + 0);
    int*   flag   = (int*)(ws + 4096);
    int*   cntinr = (int*)(ws + 8192);
    int*   ctot   = (int*)(ws + 8704);
    int*   cbase  = (int*)(ws + 9216);    // 129 ints
    float* sums   = (float*)(ws + 10240);
    int*   bh     = (int*)(ws + 16384);
    float* sorted = (float*)(ws + 16384 + (size_t)NUMC * NBLK * 4);
    int*   labels = (int*)d_out;   // staged as int32, converted by k_finish

    k_init<<<4, 256, 0, stream>>>(cen0, wcen, flag, cntinr);
    for (int it = 0; it < ITERS; ++it) {
        k_count  <<<NBLK, 256, 0, stream>>>(data, wcen, cntinr, flag);
        k_assign <<<NBLK, 256, 0, stream>>>(data, wcen, cntinr, labels, bh, flag);
        k_scan   <<<NUMC, 256, 0, stream>>>(bh, ctot, flag);
        k_base   <<<1, 64, 0, stream>>>(ctot, cbase, flag);
        k_scatter<<<NBLK, 256, 0, stream>>>(data, labels, bh, cbase, sorted, flag);
        k_sums   <<<NUMC, 64, 0, stream>>>(sorted, cbase, ctot, sums, flag);
        k_update <<<1, 256, 0, stream>>>(wcen, sums, ctot, flag, cntinr);
    }
    k_finish<<<(NPTS + NUMC * FD + 255) / 256, 256, 0, stream>>>(out, wcen);
}